// Round 13
// baseline (216.000 us; speedup 1.0000x reference)
//
#include <hip/hip_runtime.h>
#include <hip/hip_bf16.h>
#include <math.h>

#define LRELU_NEG 0.2f
#define BN_EPS 1e-5f
#define CSR_SHIFT 7

typedef __attribute__((ext_vector_type(8))) short bf16x8;
typedef __attribute__((ext_vector_type(4))) float f32x4;

__device__ __forceinline__ float lrelu(float x) { return x > 0.f ? x : LRELU_NEG * x; }
__device__ __forceinline__ float b2f(__hip_bfloat16 v) { return __bfloat162float(v); }
__device__ __forceinline__ unsigned short f2bu(float v) {
  __hip_bfloat16 b = __float2bfloat16(v);
  return *(unsigned short*)&b;
}
__device__ __forceinline__ float blo(unsigned int u) { return __uint_as_float(u << 16); }
__device__ __forceinline__ float bhi(unsigned int u) { return __uint_as_float(u & 0xFFFF0000u); }
__device__ __forceinline__ float elu_fast(float v) { return v > 0.f ? v : __expf(v) - 1.f; }
__device__ __forceinline__ float ldw(const void* p, int i, int fl) {
  return fl ? b2f(((const __hip_bfloat16*)p)[i]) : ((const float*)p)[i];
}

// ---------------- setup: dtype detect (last block) + per-block bucket histograms ----------------
__global__ __launch_bounds__(256) void k_setup(const int* __restrict__ ei, int E, int EN, int ebks,
                                               const unsigned short* __restrict__ w, int wn,
                                               int* __restrict__ flag, int* __restrict__ ph) {
  int b = blockIdx.x;
  int tid = threadIdx.x;
  if (b == ebks) {          // dtype detect
    __shared__ int bad_s;
    if (tid == 0) bad_s = 0;
    __syncthreads();
    int bad = 0;
    for (int i = 2 * tid; i < wn; i += 512) {
      unsigned short u = w[i];
      if ((u & 0x7FFF) == 0) continue;
      int ex = (u >> 7) & 0xFF;
      if (ex > 131 || ex < 90) bad++;
    }
    atomicAdd(&bad_s, bad);
    __syncthreads();
    if (tid == 0) *flag = (bad_s < 2048) ? 1 : 0;
    return;
  }
  __shared__ int hist[512];
  hist[tid] = 0; hist[tid + 256] = 0;
  __syncthreads();
  int base = b * 4096;
  for (int i = 0; i < 16; i++) {
    int e = base + i * 256 + tid;
    if (e < EN) {
      int dst = (e < E) ? ei[E + e] : (e - E);
      atomicAdd(&hist[dst >> CSR_SHIFT], 1);
    }
  }
  __syncthreads();
  ph[b * 512 + tid] = hist[tid];
  ph[b * 512 + tid + 256] = hist[tid + 256];
}

// ---------------- reduce partials + bucket scan ----------------
__global__ __launch_bounds__(512) void k_bucketscan(const int* __restrict__ ph, int ebks,
                                                    int* __restrict__ bbase, int* __restrict__ gcursor) {
  __shared__ int wpre[8];
  int tid = threadIdx.x, lane = tid & 63, wid = tid >> 6;
  int v = 0;
  for (int i = 0; i < ebks; i++) v += ph[i * 512 + tid];
  int x = v;
  #pragma unroll
  for (int off = 1; off < 64; off <<= 1) {
    int y = __shfl_up(x, off);
    if (lane >= off) x += y;
  }
  if (lane == 63) wpre[wid] = x;
  __syncthreads();
  if (tid == 0) {
    int acc = 0;
    #pragma unroll
    for (int w = 0; w < 8; w++) { int t = wpre[w]; wpre[w] = acc; acc += t; }
  }
  __syncthreads();
  int excl = wpre[wid] + x - v;
  bbase[tid] = excl;
  gcursor[tid] = excl;
  if (tid == 511) bbase[512] = excl + v;
}

// ---------------- bin scatter ----------------
__global__ __launch_bounds__(256) void k_binscatter(const int* __restrict__ ei, int* __restrict__ gcursor,
                                                    unsigned int* __restrict__ pairs, int E, int EN) {
  __shared__ int cnt[512];
  __shared__ int base[512];
  int tid = threadIdx.x;
  cnt[tid] = 0; cnt[tid + 256] = 0;
  __syncthreads();
  int eb = blockIdx.x * 4096;
  int srcs[16], dsts[16];
  #pragma unroll
  for (int i = 0; i < 16; i++) {
    int e = eb + i * 256 + tid;
    srcs[i] = -1; dsts[i] = 0;
    if (e < EN) {
      int s, d;
      if (e < E) { s = ei[e]; d = ei[E + e]; } else { s = e - E; d = s; }
      srcs[i] = s; dsts[i] = d;
      atomicAdd(&cnt[d >> CSR_SHIFT], 1);
    }
  }
  __syncthreads();
  for (int b = tid; b < 512; b += 256) {
    int c = cnt[b];
    base[b] = c ? atomicAdd(&gcursor[b], c) : 0;
    cnt[b] = 0;
  }
  __syncthreads();
  #pragma unroll
  for (int i = 0; i < 16; i++) {
    if (srcs[i] >= 0) {
      int b = dsts[i] >> CSR_SHIFT;
      int loc = atomicAdd(&cnt[b], 1);
      pairs[base[b] + loc] = ((unsigned int)srcs[i] << CSR_SHIFT) | (unsigned int)(dsts[i] & 127);
    }
  }
}

// ---------------- per-bucket rs + col scatter ----------------
__global__ __launch_bounds__(256) void k_csrfin(const unsigned int* __restrict__ pairs,
                                                const int* __restrict__ bbase,
                                                int* __restrict__ rs, int* __restrict__ col,
                                                int N, int EN) {
  __shared__ int dcount[128];
  __shared__ int wsum;
  __shared__ int lcur[128];
  int b = blockIdx.x, tid = threadIdx.x;
  if (tid < 128) dcount[tid] = 0;
  __syncthreads();
  int s = bbase[b], e = bbase[b + 1];
  for (int i = s + tid; i < e; i += 256)
    atomicAdd(&dcount[pairs[i] & 127], 1);
  __syncthreads();
  int x = 0, v = 0, wid = 0;
  if (tid < 128) {
    v = dcount[tid];
    int lane = tid & 63; wid = tid >> 6;
    x = v;
    #pragma unroll
    for (int off = 1; off < 64; off <<= 1) {
      int y = __shfl_up(x, off);
      if (lane >= off) x += y;
    }
    if (wid == 0 && lane == 63) wsum = x;
  }
  __syncthreads();
  if (tid < 128) {
    int excl = x - v + (wid ? wsum : 0);
    int r = s + excl;
    int node = (b << CSR_SHIFT) + tid;
    if (node < N) rs[node] = r;
    lcur[tid] = r;
  }
  if (b == 0 && tid == 0) rs[N] = EN;
  __syncthreads();
  for (int i = s + tid; i < e; i += 256) {
    unsigned int p = pairs[i];
    int pos = atomicAdd(&lcur[p & 127], 1);
    col[pos] = (int)(p >> CSR_SHIFT);
  }
}

// ---------------- weight folding from RAW inputs + BN affine precompute ----------------
struct FoldArgs {
  const void *W0, *as0, *ad0, *W1, *as1, *ad1, *W2, *as2, *ad2;
  const void *bn[15];    // b0,g0,bb0,bm0,bv0,  b1..,  b2..
  float* W0p; __hip_bfloat16* Wt1; __hip_bfloat16* Wt2;
  float *A0, *B0, *A1, *B1, *A2, *B2;
};

__global__ __launch_bounds__(256) void k_foldW(FoldArgs fa, const int* __restrict__ flag) {
  int idx = blockIdx.x * 256 + threadIdx.x;
  int fl = *flag;
  if (idx < 576) {                  // W0p [4][144]
    int k = idx / 144, c = idx % 144;
    float v = 0.f;
    if (c < 128) v = ldw(fa.W0, k * 128 + c, fl);
    else if (c < 136) {
      int hh = (c - 128) & 3; const void* a = (c < 132) ? fa.as0 : fa.ad0;
      float s = 0.f;
      for (int cc = 0; cc < 32; cc++)
        s += ldw(fa.W0, k * 128 + hh * 32 + cc, fl) * ldw(a, hh * 32 + cc, fl);
      v = s;
    }
    fa.W0p[k * 144 + c] = v;
    return;
  }
  idx -= 576;
  if (idx < 144 * 128) {            // Wt1 [144][128]
    int c = idx >> 7, k = idx & 127;
    float v = 0.f;
    if (c < 128) v = ldw(fa.W1, k * 128 + c, fl);
    else if (c < 136) {
      int hh = (c - 128) & 3; const void* a = (c < 132) ? fa.as1 : fa.ad1;
      float s = 0.f;
      for (int cc = 0; cc < 32; cc++)
        s += ldw(fa.W1, k * 128 + hh * 32 + cc, fl) * ldw(a, hh * 32 + cc, fl);
      v = s;
    }
    fa.Wt1[c * 128 + k] = __float2bfloat16(v);
    return;
  }
  idx -= 144 * 128;
  if (idx < 48 * 128) {             // Wt2 [48][128]
    int c = idx >> 7, k = idx & 127;
    float v = 0.f;
    if (c < 32) v = ldw(fa.W2, k * 32 + c, fl);
    else if (c == 32) { float s = 0.f; for (int cc = 0; cc < 32; cc++) s += ldw(fa.W2, k * 32 + cc, fl) * ldw(fa.as2, cc, fl); v = s; }
    else if (c == 33) { float s = 0.f; for (int cc = 0; cc < 32; cc++) s += ldw(fa.W2, k * 32 + cc, fl) * ldw(fa.ad2, cc, fl); v = s; }
    fa.Wt2[c * 128 + k] = __float2bfloat16(v);
    return;
  }
  idx -= 48 * 128;
  if (idx < 128) {                  // AB0
    float A = ldw(fa.bn[1], idx, fl) * rsqrtf(ldw(fa.bn[4], idx, fl) + BN_EPS);
    fa.A0[idx] = A;
    fa.B0[idx] = (ldw(fa.bn[0], idx, fl) - ldw(fa.bn[3], idx, fl)) * A + ldw(fa.bn[2], idx, fl);
    return;
  }
  idx -= 128;
  if (idx < 128) {                  // AB1
    float A = ldw(fa.bn[6], idx, fl) * rsqrtf(ldw(fa.bn[9], idx, fl) + BN_EPS);
    fa.A1[idx] = A;
    fa.B1[idx] = (ldw(fa.bn[5], idx, fl) - ldw(fa.bn[8], idx, fl)) * A + ldw(fa.bn[7], idx, fl);
    return;
  }
  idx -= 128;
  if (idx < 32) {                   // AB2
    float A = ldw(fa.bn[11], idx, fl) * rsqrtf(ldw(fa.bn[14], idx, fl) + BN_EPS);
    fa.A2[idx] = A;
    fa.B2[idx] = (ldw(fa.bn[10], idx, fl) - ldw(fa.bn[13], idx, fl)) * A + ldw(fa.bn[12], idx, fl);
  }
}

// ---------------- layer-0 GEMM (K=4), raw x, folded logits ----------------
__global__ __launch_bounds__(256) void k_gemm0(const void* __restrict__ x, const float* __restrict__ W0p,
    const int* __restrict__ flag,
    __hip_bfloat16* __restrict__ h, float* __restrict__ als, float* __restrict__ ald, int N) {
  int t = blockIdx.x * 256 + threadIdx.x;
  int nrow = t / 36, cg = t - nrow * 36;
  if (nrow >= N) return;
  float4 xv;
  if (*flag) {
    uint2 tv = ((const uint2*)x)[nrow];
    xv = make_float4(blo(tv.x), bhi(tv.x), blo(tv.y), bhi(tv.y));
  } else {
    xv = ((const float4*)x)[nrow];
  }
  int c0 = cg * 4;
  float o[4];
  #pragma unroll
  for (int j = 0; j < 4; j++) {
    int c = c0 + j;
    o[j] = fmaf(xv.x, W0p[c], fmaf(xv.y, W0p[144 + c], fmaf(xv.z, W0p[288 + c], xv.w * W0p[432 + c])));
  }
  if (c0 < 128) {
    uint2 pk;
    pk.x = ((unsigned int)f2bu(o[1]) << 16) | f2bu(o[0]);
    pk.y = ((unsigned int)f2bu(o[3]) << 16) | f2bu(o[2]);
    *((uint2*)((unsigned short*)h + (size_t)nrow * 128) + cg) = pk;
  } else if (c0 == 128) {
    *(float4*)(als + (size_t)nrow * 4) = make_float4(o[0], o[1], o[2], o[3]);
  } else {
    *(float4*)(ald + (size_t)nrow * 4) = make_float4(o[0], o[1], o[2], o[3]);
  }
}

// ---------------- MFMA GEMM ----------------
template <int CT, int DOUT, int HEADS>
__global__ __launch_bounds__(256) void k_mm(const __hip_bfloat16* __restrict__ xa,
    const __hip_bfloat16* __restrict__ Wt,
    __hip_bfloat16* __restrict__ h, float* __restrict__ als, float* __restrict__ ald, int N) {
  __shared__ unsigned short A_s[64 * 128];
  __shared__ unsigned short B_s[CT * 16 * 128];
  int tid = threadIdx.x;
  int row0 = blockIdx.x * 64;

  for (int i = tid; i < 1024; i += 256) {
    int r = i >> 4, slot = i & 15;
    int gr = row0 + r;
    float4 v = make_float4(0.f, 0.f, 0.f, 0.f);
    if (gr < N) v = ((const float4*)(xa + (size_t)gr * 128))[slot];
    *(float4*)((char*)A_s + r * 256 + ((slot ^ (r & 7)) << 4)) = v;
  }
  for (int i = tid; i < CT * 256; i += 256) {
    int r = i >> 4, slot = i & 15;
    float4 v = ((const float4*)Wt)[i];
    *(float4*)((char*)B_s + r * 256 + ((slot ^ (r & 7)) << 4)) = v;
  }
  __syncthreads();

  int l = tid & 63, w = tid >> 6;
  int lr = l & 15, lg = l >> 4;
  f32x4 acc[CT];
  #pragma unroll
  for (int ct = 0; ct < CT; ct++) acc[ct] = (f32x4){0.f, 0.f, 0.f, 0.f};

  int rA = w * 16 + lr;
  #pragma unroll
  for (int k0 = 0; k0 < 4; k0++) {
    int slot = k0 * 4 + lg;
    bf16x8 a = *(const bf16x8*)((const char*)A_s + rA * 256 + ((slot ^ (rA & 7)) << 4));
    #pragma unroll
    for (int ct = 0; ct < CT; ct++) {
      int rB = ct * 16 + lr;
      bf16x8 b = *(const bf16x8*)((const char*)B_s + rB * 256 + ((slot ^ (rB & 7)) << 4));
      acc[ct] = __builtin_amdgcn_mfma_f32_16x16x32_bf16(a, b, acc[ct], 0, 0, 0);
    }
  }

  #pragma unroll
  for (int ct = 0; ct < CT; ct++) {
    #pragma unroll
    for (int j = 0; j < 4; j++) {
      int gr = row0 + w * 16 + lg * 4 + j;
      if (gr >= N) continue;
      int col = ct * 16 + lr;
      float v = acc[ct][j];
      if (col < DOUT)                 h[(size_t)gr * DOUT + col] = __float2bfloat16(v);
      else if (col < DOUT + HEADS)    als[(size_t)gr * HEADS + (col - DOUT)] = v;
      else if (col < DOUT + 2*HEADS)  ald[(size_t)gr * HEADS + (col - DOUT - HEADS)] = v;
    }
  }
}

// ---------------- aggregation, H=4 C=32: 32-lane group per node, BN-folded epilogue ----------------
__global__ __launch_bounds__(256) void k_agg4(const __hip_bfloat16* __restrict__ h, const float* __restrict__ als,
    const float* __restrict__ ald, const int* __restrict__ rs, const int* __restrict__ col,
    const float* __restrict__ Aarr, const float* __restrict__ Barr,
    __hip_bfloat16* __restrict__ out, int N) {
  __shared__ int svs[8][32];
  __shared__ float ps[8][32][4];
  int tid = threadIdx.x;
  int sub = tid & 31, gi = tid >> 5;
  int n = blockIdx.x * 8 + gi;
  if (n >= N) return;
  int row = rs[n], deg = rs[n + 1] - row;
  float4 ad4 = *(const float4*)(ald + (size_t)n * 4);
  int hh2 = sub >> 3;
  float acc0 = 0.f, acc1 = 0.f, acc2 = 0.f, acc3 = 0.f;
  float s0 = 0.f, s1 = 0.f, s2 = 0.f, s3 = 0.f;

  for (int base = 0; base < deg; base += 32) {
    int k = base + sub;
    int sv = 0; float q0 = 0.f, q1 = 0.f, q2 = 0.f, q3 = 0.f;
    if (k < deg) {
      sv = col[row + k];
      float4 a4 = *(const float4*)(als + (size_t)sv * 4);
      q0 = __expf(lrelu(a4.x + ad4.x));
      q1 = __expf(lrelu(a4.y + ad4.y));
      q2 = __expf(lrelu(a4.z + ad4.z));
      q3 = __expf(lrelu(a4.w + ad4.w));
    }
    svs[gi][sub] = sv;
    *(float4*)&ps[gi][sub][0] = make_float4(q0, q1, q2, q3);
    s0 += q0; s1 += q1; s2 += q2; s3 += q3;
    int cnt = min(32, deg - base);
    int e = 0;
    for (; e + 3 < cnt; e += 4) {
      float pA = ps[gi][e][hh2];     int sA = svs[gi][e];
      float pB = ps[gi][e + 1][hh2]; int sB = svs[gi][e + 1];
      float pC = ps[gi][e + 2][hh2]; int sC = svs[gi][e + 2];
      float pD = ps[gi][e + 3][hh2]; int sD = svs[gi][e + 3];
      uint2 hA = *((const uint2*)(h + (size_t)sA * 128) + sub);
      uint2 hB = *((const uint2*)(h + (size_t)sB * 128) + sub);
      uint2 hC = *((const uint2*)(h + (size_t)sC * 128) + sub);
      uint2 hD = *((const uint2*)(h + (size_t)sD * 128) + sub);
      acc0 = fmaf(pA, blo(hA.x), acc0); acc1 = fmaf(pA, bhi(hA.x), acc1);
      acc2 = fmaf(pA, blo(hA.y), acc2); acc3 = fmaf(pA, bhi(hA.y), acc3);
      acc0 = fmaf(pB, blo(hB.x), acc0); acc1 = fmaf(pB, bhi(hB.x), acc1);
      acc2 = fmaf(pB, blo(hB.y), acc2); acc3 = fmaf(pB, bhi(hB.y), acc3);
      acc0 = fmaf(pC, blo(hC.x), acc0); acc1 = fmaf(pC, bhi(hC.x), acc1);
      acc2 = fmaf(pC, blo(hC.y), acc2); acc3 = fmaf(pC, bhi(hC.y), acc3);
      acc0 = fmaf(pD, blo(hD.x), acc0); acc1 = fmaf(pD, bhi(hD.x), acc1);
      acc2 = fmaf(pD, blo(hD.y), acc2); acc3 = fmaf(pD, bhi(hD.y), acc3);
    }
    for (; e < cnt; e++) {
      float pA = ps[gi][e][hh2]; int sA = svs[gi][e];
      uint2 hA = *((const uint2*)(h + (size_t)sA * 128) + sub);
      acc0 = fmaf(pA, blo(hA.x), acc0); acc1 = fmaf(pA, bhi(hA.x), acc1);
      acc2 = fmaf(pA, blo(hA.y), acc2); acc3 = fmaf(pA, bhi(hA.y), acc3);
    }
  }
  #pragma unroll
  for (int off = 1; off < 32; off <<= 1) {
    s0 += __shfl_xor(s0, off); s1 += __shfl_xor(s1, off);
    s2 += __shfl_xor(s2, off); s3 += __shfl_xor(s3, off);
  }
  float ssel = hh2 == 0 ? s0 : hh2 == 1 ? s1 : hh2 == 2 ? s2 : s3;
  float inv = 1.f / (ssel + 1e-16f);

  int c0 = 4 * sub;
  float4 Av = *(const float4*)(Aarr + c0);
  float4 Bv = *(const float4*)(Barr + c0);
  float v0 = acc0 * inv * Av.x + Bv.x;
  float v1 = acc1 * inv * Av.y + Bv.y;
  float v2 = acc2 * inv * Av.z + Bv.z;
  float v3 = acc3 * inv * Av.w + Bv.w;
  v0 = elu_fast(v0); v1 = elu_fast(v1); v2 = elu_fast(v2); v3 = elu_fast(v3);
  uint2 packed;
  packed.x = ((unsigned int)f2bu(v1) << 16) | f2bu(v0);
  packed.y = ((unsigned int)f2bu(v3) << 16) | f2bu(v2);
  *((uint2*)((unsigned short*)out + (size_t)n * 128) + sub) = packed;
}

// ---------------- fused aggregation H=1 + pooling + MLP head (block per graph) ----------------
__global__ __launch_bounds__(256) void k_agg1pool(const __hip_bfloat16* __restrict__ h,
    const float* __restrict__ als, const float* __restrict__ ald,
    const int* __restrict__ rs, const int* __restrict__ col,
    const float* __restrict__ A2, const float* __restrict__ B2,
    const int* __restrict__ batch,
    const void* __restrict__ u, const void* __restrict__ l1w, const void* __restrict__ l1b,
    const void* __restrict__ l2w, const void* __restrict__ l2b, const int* __restrict__ flag,
    float* __restrict__ out, int N, int G) {
  __shared__ int svs[16][16];
  __shared__ float ps[16][16];
  __shared__ float rsum[16][32];
  __shared__ float rmax[16][32];
  __shared__ float comb[74];
  int g = blockIdx.x;
  int tid = threadIdx.x, sub = tid & 15, gi = tid >> 4;
  // graph node range
  int lo = 0, hi = N;
  while (lo < hi) { int mid = (lo + hi) >> 1; if (batch[mid] < g) lo = mid + 1; else hi = mid; }
  int start = lo;
  hi = N;
  while (lo < hi) { int mid = (lo + hi) >> 1; if (batch[mid] < g + 1) lo = mid + 1; else hi = mid; }
  int end = lo;

  float2 Af = *(const float2*)(A2 + 2 * sub);
  float2 Bf = *(const float2*)(B2 + 2 * sub);
  float sum0 = 0.f, sum1 = 0.f, mx0 = -1e30f, mx1 = -1e30f;

  for (int n = start + gi; n < end; n += 16) {
    int row = rs[n], deg = rs[n + 1] - row;
    float ad = ald[n];
    float acc0 = 0.f, acc1 = 0.f, s = 0.f;
    for (int base = 0; base < deg; base += 16) {
      int k = base + sub;
      int sv = 0; float q = 0.f;
      if (k < deg) {
        sv = col[row + k];
        q = __expf(lrelu(als[sv] + ad));
      }
      svs[gi][sub] = sv;
      ps[gi][sub] = q;
      s += q;
      int cnt = min(16, deg - base);
      int e = 0;
      for (; e + 3 < cnt; e += 4) {
        float pA = ps[gi][e];     int sA = svs[gi][e];
        float pB = ps[gi][e + 1]; int sB = svs[gi][e + 1];
        float pC = ps[gi][e + 2]; int sC = svs[gi][e + 2];
        float pD = ps[gi][e + 3]; int sD = svs[gi][e + 3];
        unsigned int hA = *((const unsigned int*)(h + (size_t)sA * 32) + sub);
        unsigned int hB = *((const unsigned int*)(h + (size_t)sB * 32) + sub);
        unsigned int hC = *((const unsigned int*)(h + (size_t)sC * 32) + sub);
        unsigned int hD = *((const unsigned int*)(h + (size_t)sD * 32) + sub);
        acc0 = fmaf(pA, blo(hA), acc0); acc1 = fmaf(pA, bhi(hA), acc1);
        acc0 = fmaf(pB, blo(hB), acc0); acc1 = fmaf(pB, bhi(hB), acc1);
        acc0 = fmaf(pC, blo(hC), acc0); acc1 = fmaf(pC, bhi(hC), acc1);
        acc0 = fmaf(pD, blo(hD), acc0); acc1 = fmaf(pD, bhi(hD), acc1);
      }
      for (; e < cnt; e++) {
        float pA = ps[gi][e]; int sA = svs[gi][e];
        unsigned int hA = *((const unsigned int*)(h + (size_t)sA * 32) + sub);
        acc0 = fmaf(pA, blo(hA), acc0); acc1 = fmaf(pA, bhi(hA), acc1);
      }
    }
    #pragma unroll
    for (int off = 1; off < 16; off <<= 1) s += __shfl_xor(s, off);
    float inv = 1.f / (s + 1e-16f);
    float v0 = acc0 * inv * Af.x + Bf.x;
    float v1 = acc1 * inv * Af.y + Bf.y;
    v0 = elu_fast(v0);
    v1 = elu_fast(v1);
    sum0 += v0; sum1 += v1;
    mx0 = fmaxf(mx0, v0); mx1 = fmaxf(mx1, v1);
  }
  rsum[gi][2 * sub] = sum0; rsum[gi][2 * sub + 1] = sum1;
  rmax[gi][2 * sub] = mx0;  rmax[gi][2 * sub + 1] = mx1;
  __syncthreads();
  int fl = *flag;
  if (tid < 32) {
    float s = 0.f, m = -1e30f;
    #pragma unroll
    for (int i = 0; i < 16; i++) { s += rsum[i][tid]; m = fmaxf(m, rmax[i][tid]); }
    float cnt = (float)(end - start);
    comb[tid] = s / cnt;
    comb[32 + tid] = m;
  }
  if (tid < 10) comb[64 + tid] = ldw(u, g * 10 + tid, fl);
  __syncthreads();
  if (tid < 32) {
    float acc = ldw(l1b, tid, fl);
    #pragma unroll
    for (int k = 0; k < 74; k++) acc = fmaf(comb[k], ldw(l1w, k * 32 + tid, fl), acc);
    acc = fmaxf(acc, 0.f);
    float v = acc * ldw(l2w, tid, fl);
    #pragma unroll
    for (int off = 16; off; off >>= 1) v += __shfl_xor(v, off, 32);
    if (tid == 0) out[g] = 1.f / (1.f + __expf(-(v + ldw(l2b, 0, fl))));
  }
}

extern "C" void kernel_launch(void* const* d_in, const int* in_sizes, int n_in,
                              void* d_out, int out_size, void* d_ws, size_t ws_size,
                              hipStream_t stream) {
  const int* EI    = (const int*)d_in[1];
  const int* BATCH = (const int*)d_in[2];
  float* OUT = (float*)d_out;

  int N = in_sizes[2];
  int E = in_sizes[1] / 2;
  int G = in_sizes[3] / 10;
  int EN = E + N;
  int NB = (N + 127) >> 7;
  int ebks = (EN + 4095) / 4096;

  char* ws = (char*)d_ws;
  size_t off = 0;
  auto alloc = [&](size_t bytes) {
    void* p = ws + off;
    off = (off + bytes + 255) & ~(size_t)255;
    return p;
  };
  __hip_bfloat16* f_xa = (__hip_bfloat16*)alloc((size_t)N * 128 * 2);
  __hip_bfloat16* f_h  = (__hip_bfloat16*)alloc((size_t)N * 128 * 2);
  float* f_als = (float*)alloc((size_t)N * 4 * 4);
  float* f_ald = (float*)alloc((size_t)N * 4 * 4);
  float* fW0p  = (float*)alloc(576 * 4);
  __hip_bfloat16* fWt1 = (__hip_bfloat16*)alloc(144 * 128 * 2);
  __hip_bfloat16* fWt2 = (__hip_bfloat16*)alloc(48 * 128 * 2);
  float* fA0 = (float*)alloc(128 * 4);
  float* fB0 = (float*)alloc(128 * 4);
  float* fA1 = (float*)alloc(128 * 4);
  float* fB1 = (float*)alloc(128 * 4);
  float* fA2 = (float*)alloc(32 * 4);
  float* fB2 = (float*)alloc(32 * 4);
  int* i_rs   = (int*)alloc((size_t)(N + 1) * 4);
  int* i_col  = (int*)alloc((size_t)EN * 4);
  unsigned int* i_pairs = (unsigned int*)alloc((size_t)EN * 4);
  int* i_ph      = (int*)alloc((size_t)ebks * 512 * 4);
  int* i_bbase   = (int*)alloc(513 * 4);
  int* i_gcursor = (int*)alloc(512 * 4);
  int* i_flag = (int*)alloc(256);

  // setup: dtype detect + per-block histograms
  k_setup<<<ebks + 1, 256, 0, stream>>>(EI, E, EN, ebks,
                                        (const unsigned short*)d_in[12], in_sizes[12],
                                        i_flag, i_ph);
  // weight folding (raw inputs, needs flag)
  FoldArgs fa;
  fa.W0 = d_in[4];  fa.as0 = d_in[5];  fa.ad0 = d_in[6];
  fa.W1 = d_in[12]; fa.as1 = d_in[13]; fa.ad1 = d_in[14];
  fa.W2 = d_in[20]; fa.as2 = d_in[21]; fa.ad2 = d_in[22];
  for (int i = 0; i < 5; i++) {
    fa.bn[i]      = d_in[7 + i];
    fa.bn[5 + i]  = d_in[15 + i];
    fa.bn[10 + i] = d_in[23 + i];
  }
  fa.W0p = fW0p; fa.Wt1 = fWt1; fa.Wt2 = fWt2;
  fa.A0 = fA0; fa.B0 = fB0; fa.A1 = fA1; fa.B1 = fB1; fa.A2 = fA2; fa.B2 = fB2;
  k_foldW<<<100, 256, 0, stream>>>(fa, i_flag);

  // CSR build
  k_bucketscan<<<1, 512, 0, stream>>>(i_ph, ebks, i_bbase, i_gcursor);
  k_binscatter<<<ebks, 256, 0, stream>>>(EI, i_gcursor, i_pairs, E, EN);
  k_csrfin<<<NB, 256, 0, stream>>>(i_pairs, i_bbase, i_rs, i_col, N, EN);

  // layer 0
  k_gemm0<<<(N * 36 + 255) / 256, 256, 0, stream>>>(d_in[0], fW0p, i_flag, f_h, f_als, f_ald, N);
  k_agg4<<<(N + 7) / 8, 256, 0, stream>>>(f_h, f_als, f_ald, i_rs, i_col, fA0, fB0, f_xa, N);
  // layer 1 (MFMA)
  k_mm<9, 128, 4><<<(N + 63) / 64, 256, 0, stream>>>(f_xa, fWt1, f_h, f_als, f_ald, N);
  k_agg4<<<(N + 7) / 8, 256, 0, stream>>>(f_h, f_als, f_ald, i_rs, i_col, fA1, fB1, f_xa, N);
  // layer 2 (MFMA)
  k_mm<3, 32, 1><<<(N + 63) / 64, 256, 0, stream>>>(f_xa, fWt2, f_h, f_als, f_ald, N);
  // fused agg1 + pooling + MLP
  k_agg1pool<<<G, 256, 0, stream>>>(f_h, f_als, f_ald, i_rs, i_col, fA2, fB2,
                                    BATCH, d_in[3], d_in[28], d_in[29], d_in[30], d_in[31],
                                    i_flag, OUT, N, G);
}

// Round 14
// 211.268 us; speedup vs baseline: 1.0224x; 1.0224x over previous
//
#include <hip/hip_runtime.h>
#include <hip/hip_bf16.h>
#include <math.h>

#define LRELU_NEG 0.2f
#define BN_EPS 1e-5f
#define CSR_SHIFT 7

typedef __attribute__((ext_vector_type(8))) short bf16x8;
typedef __attribute__((ext_vector_type(4))) float f32x4;

__device__ __forceinline__ float lrelu(float x) { return x > 0.f ? x : LRELU_NEG * x; }
__device__ __forceinline__ float b2f(__hip_bfloat16 v) { return __bfloat162float(v); }
__device__ __forceinline__ unsigned short f2bu(float v) {
  __hip_bfloat16 b = __float2bfloat16(v);
  return *(unsigned short*)&b;
}
__device__ __forceinline__ float blo(unsigned int u) { return __uint_as_float(u << 16); }
__device__ __forceinline__ float bhi(unsigned int u) { return __uint_as_float(u & 0xFFFF0000u); }
__device__ __forceinline__ float elu_fast(float v) { return v > 0.f ? v : __expf(v) - 1.f; }
__device__ __forceinline__ float ldw(const void* p, int i, int fl) {
  return fl ? b2f(((const __hip_bfloat16*)p)[i]) : ((const float*)p)[i];
}

// ---------------- setup: dtype detect (last block) + per-block bucket histograms ----------------
__global__ __launch_bounds__(256) void k_setup(const int* __restrict__ ei, int E, int EN, int ebks,
                                               const unsigned short* __restrict__ w, int wn,
                                               int* __restrict__ flag, int* __restrict__ ph) {
  int b = blockIdx.x;
  int tid = threadIdx.x;
  if (b == ebks) {          // dtype detect
    __shared__ int bad_s;
    if (tid == 0) bad_s = 0;
    __syncthreads();
    int bad = 0;
    for (int i = 2 * tid; i < wn; i += 512) {
      unsigned short u = w[i];
      if ((u & 0x7FFF) == 0) continue;
      int ex = (u >> 7) & 0xFF;
      if (ex > 131 || ex < 90) bad++;
    }
    atomicAdd(&bad_s, bad);
    __syncthreads();
    if (tid == 0) *flag = (bad_s < 2048) ? 1 : 0;
    return;
  }
  __shared__ int hist[512];
  hist[tid] = 0; hist[tid + 256] = 0;
  __syncthreads();
  int base = b * 4096;
  for (int i = 0; i < 16; i++) {
    int e = base + i * 256 + tid;
    if (e < EN) {
      int dst = (e < E) ? ei[E + e] : (e - E);
      atomicAdd(&hist[dst >> CSR_SHIFT], 1);
    }
  }
  __syncthreads();
  ph[b * 512 + tid] = hist[tid];
  ph[b * 512 + tid + 256] = hist[tid + 256];
}

// ---------------- reduce partials + bucket scan ----------------
__global__ __launch_bounds__(512) void k_bucketscan(const int* __restrict__ ph, int ebks,
                                                    int* __restrict__ bbase, int* __restrict__ gcursor) {
  __shared__ int wpre[8];
  int tid = threadIdx.x, lane = tid & 63, wid = tid >> 6;
  int v = 0;
  for (int i = 0; i < ebks; i++) v += ph[i * 512 + tid];
  int x = v;
  #pragma unroll
  for (int off = 1; off < 64; off <<= 1) {
    int y = __shfl_up(x, off);
    if (lane >= off) x += y;
  }
  if (lane == 63) wpre[wid] = x;
  __syncthreads();
  if (tid == 0) {
    int acc = 0;
    #pragma unroll
    for (int w = 0; w < 8; w++) { int t = wpre[w]; wpre[w] = acc; acc += t; }
  }
  __syncthreads();
  int excl = wpre[wid] + x - v;
  bbase[tid] = excl;
  gcursor[tid] = excl;
  if (tid == 511) bbase[512] = excl + v;
}

// ---------------- bin scatter ----------------
__global__ __launch_bounds__(256) void k_binscatter(const int* __restrict__ ei, int* __restrict__ gcursor,
                                                    unsigned int* __restrict__ pairs, int E, int EN) {
  __shared__ int cnt[512];
  __shared__ int base[512];
  int tid = threadIdx.x;
  cnt[tid] = 0; cnt[tid + 256] = 0;
  __syncthreads();
  int eb = blockIdx.x * 4096;
  int srcs[16], dsts[16];
  #pragma unroll
  for (int i = 0; i < 16; i++) {
    int e = eb + i * 256 + tid;
    srcs[i] = -1; dsts[i] = 0;
    if (e < EN) {
      int s, d;
      if (e < E) { s = ei[e]; d = ei[E + e]; } else { s = e - E; d = s; }
      srcs[i] = s; dsts[i] = d;
      atomicAdd(&cnt[d >> CSR_SHIFT], 1);
    }
  }
  __syncthreads();
  for (int b = tid; b < 512; b += 256) {
    int c = cnt[b];
    base[b] = c ? atomicAdd(&gcursor[b], c) : 0;
    cnt[b] = 0;
  }
  __syncthreads();
  #pragma unroll
  for (int i = 0; i < 16; i++) {
    if (srcs[i] >= 0) {
      int b = dsts[i] >> CSR_SHIFT;
      int loc = atomicAdd(&cnt[b], 1);
      pairs[base[b] + loc] = ((unsigned int)srcs[i] << CSR_SHIFT) | (unsigned int)(dsts[i] & 127);
    }
  }
}

// ---------------- per-bucket rs + col scatter ----------------
__global__ __launch_bounds__(256) void k_csrfin(const unsigned int* __restrict__ pairs,
                                                const int* __restrict__ bbase,
                                                int* __restrict__ rs, int* __restrict__ col,
                                                int N, int EN) {
  __shared__ int dcount[128];
  __shared__ int wsum;
  __shared__ int lcur[128];
  int b = blockIdx.x, tid = threadIdx.x;
  if (tid < 128) dcount[tid] = 0;
  __syncthreads();
  int s = bbase[b], e = bbase[b + 1];
  for (int i = s + tid; i < e; i += 256)
    atomicAdd(&dcount[pairs[i] & 127], 1);
  __syncthreads();
  int x = 0, v = 0, wid = 0;
  if (tid < 128) {
    v = dcount[tid];
    int lane = tid & 63; wid = tid >> 6;
    x = v;
    #pragma unroll
    for (int off = 1; off < 64; off <<= 1) {
      int y = __shfl_up(x, off);
      if (lane >= off) x += y;
    }
    if (wid == 0 && lane == 63) wsum = x;
  }
  __syncthreads();
  if (tid < 128) {
    int excl = x - v + (wid ? wsum : 0);
    int r = s + excl;
    int node = (b << CSR_SHIFT) + tid;
    if (node < N) rs[node] = r;
    lcur[tid] = r;
  }
  if (b == 0 && tid == 0) rs[N] = EN;
  __syncthreads();
  for (int i = s + tid; i < e; i += 256) {
    unsigned int p = pairs[i];
    int pos = atomicAdd(&lcur[p & 127], 1);
    col[pos] = (int)(p >> CSR_SHIFT);
  }
}

// ---------------- weight folding from RAW inputs + BN affine precompute ----------------
struct FoldArgs {
  const void *W0, *as0, *ad0, *W1, *as1, *ad1, *W2, *as2, *ad2;
  const void *bn[15];    // b0,g0,bb0,bm0,bv0,  b1..,  b2..
  float* W0p; __hip_bfloat16* Wt1; __hip_bfloat16* Wt2;
  float *A0, *B0, *A1, *B1, *A2, *B2;
};

__global__ __launch_bounds__(256) void k_foldW(FoldArgs fa, const int* __restrict__ flag) {
  int idx = blockIdx.x * 256 + threadIdx.x;
  int fl = *flag;
  if (idx < 576) {                  // W0p [4][144]
    int k = idx / 144, c = idx % 144;
    float v = 0.f;
    if (c < 128) v = ldw(fa.W0, k * 128 + c, fl);
    else if (c < 136) {
      int hh = (c - 128) & 3; const void* a = (c < 132) ? fa.as0 : fa.ad0;
      float s = 0.f;
      for (int cc = 0; cc < 32; cc++)
        s += ldw(fa.W0, k * 128 + hh * 32 + cc, fl) * ldw(a, hh * 32 + cc, fl);
      v = s;
    }
    fa.W0p[k * 144 + c] = v;
    return;
  }
  idx -= 576;
  if (idx < 144 * 128) {            // Wt1 [144][128]
    int c = idx >> 7, k = idx & 127;
    float v = 0.f;
    if (c < 128) v = ldw(fa.W1, k * 128 + c, fl);
    else if (c < 136) {
      int hh = (c - 128) & 3; const void* a = (c < 132) ? fa.as1 : fa.ad1;
      float s = 0.f;
      for (int cc = 0; cc < 32; cc++)
        s += ldw(fa.W1, k * 128 + hh * 32 + cc, fl) * ldw(a, hh * 32 + cc, fl);
      v = s;
    }
    fa.Wt1[c * 128 + k] = __float2bfloat16(v);
    return;
  }
  idx -= 144 * 128;
  if (idx < 48 * 128) {             // Wt2 [48][128]
    int c = idx >> 7, k = idx & 127;
    float v = 0.f;
    if (c < 32) v = ldw(fa.W2, k * 32 + c, fl);
    else if (c == 32) { float s = 0.f; for (int cc = 0; cc < 32; cc++) s += ldw(fa.W2, k * 32 + cc, fl) * ldw(fa.as2, cc, fl); v = s; }
    else if (c == 33) { float s = 0.f; for (int cc = 0; cc < 32; cc++) s += ldw(fa.W2, k * 32 + cc, fl) * ldw(fa.ad2, cc, fl); v = s; }
    fa.Wt2[c * 128 + k] = __float2bfloat16(v);
    return;
  }
  idx -= 48 * 128;
  if (idx < 128) {                  // AB0
    float A = ldw(fa.bn[1], idx, fl) * rsqrtf(ldw(fa.bn[4], idx, fl) + BN_EPS);
    fa.A0[idx] = A;
    fa.B0[idx] = (ldw(fa.bn[0], idx, fl) - ldw(fa.bn[3], idx, fl)) * A + ldw(fa.bn[2], idx, fl);
    return;
  }
  idx -= 128;
  if (idx < 128) {                  // AB1
    float A = ldw(fa.bn[6], idx, fl) * rsqrtf(ldw(fa.bn[9], idx, fl) + BN_EPS);
    fa.A1[idx] = A;
    fa.B1[idx] = (ldw(fa.bn[5], idx, fl) - ldw(fa.bn[8], idx, fl)) * A + ldw(fa.bn[7], idx, fl);
    return;
  }
  idx -= 128;
  if (idx < 32) {                   // AB2
    float A = ldw(fa.bn[11], idx, fl) * rsqrtf(ldw(fa.bn[14], idx, fl) + BN_EPS);
    fa.A2[idx] = A;
    fa.B2[idx] = (ldw(fa.bn[10], idx, fl) - ldw(fa.bn[13], idx, fl)) * A + ldw(fa.bn[12], idx, fl);
  }
}

// ---------------- layer-0 GEMM (K=4), raw x, folded logits ----------------
__global__ __launch_bounds__(256) void k_gemm0(const void* __restrict__ x, const float* __restrict__ W0p,
    const int* __restrict__ flag,
    __hip_bfloat16* __restrict__ h, float* __restrict__ als, float* __restrict__ ald, int N) {
  int t = blockIdx.x * 256 + threadIdx.x;
  int nrow = t / 36, cg = t - nrow * 36;
  if (nrow >= N) return;
  float4 xv;
  if (*flag) {
    uint2 tv = ((const uint2*)x)[nrow];
    xv = make_float4(blo(tv.x), bhi(tv.x), blo(tv.y), bhi(tv.y));
  } else {
    xv = ((const float4*)x)[nrow];
  }
  int c0 = cg * 4;
  float o[4];
  #pragma unroll
  for (int j = 0; j < 4; j++) {
    int c = c0 + j;
    o[j] = fmaf(xv.x, W0p[c], fmaf(xv.y, W0p[144 + c], fmaf(xv.z, W0p[288 + c], xv.w * W0p[432 + c])));
  }
  if (c0 < 128) {
    uint2 pk;
    pk.x = ((unsigned int)f2bu(o[1]) << 16) | f2bu(o[0]);
    pk.y = ((unsigned int)f2bu(o[3]) << 16) | f2bu(o[2]);
    *((uint2*)((unsigned short*)h + (size_t)nrow * 128) + cg) = pk;
  } else if (c0 == 128) {
    *(float4*)(als + (size_t)nrow * 4) = make_float4(o[0], o[1], o[2], o[3]);
  } else {
    *(float4*)(ald + (size_t)nrow * 4) = make_float4(o[0], o[1], o[2], o[3]);
  }
}

// ---------------- MFMA GEMM ----------------
template <int CT, int DOUT, int HEADS>
__global__ __launch_bounds__(256) void k_mm(const __hip_bfloat16* __restrict__ xa,
    const __hip_bfloat16* __restrict__ Wt,
    __hip_bfloat16* __restrict__ h, float* __restrict__ als, float* __restrict__ ald, int N) {
  __shared__ unsigned short A_s[64 * 128];
  __shared__ unsigned short B_s[CT * 16 * 128];
  int tid = threadIdx.x;
  int row0 = blockIdx.x * 64;

  for (int i = tid; i < 1024; i += 256) {
    int r = i >> 4, slot = i & 15;
    int gr = row0 + r;
    float4 v = make_float4(0.f, 0.f, 0.f, 0.f);
    if (gr < N) v = ((const float4*)(xa + (size_t)gr * 128))[slot];
    *(float4*)((char*)A_s + r * 256 + ((slot ^ (r & 7)) << 4)) = v;
  }
  for (int i = tid; i < CT * 256; i += 256) {
    int r = i >> 4, slot = i & 15;
    float4 v = ((const float4*)Wt)[i];
    *(float4*)((char*)B_s + r * 256 + ((slot ^ (r & 7)) << 4)) = v;
  }
  __syncthreads();

  int l = tid & 63, w = tid >> 6;
  int lr = l & 15, lg = l >> 4;
  f32x4 acc[CT];
  #pragma unroll
  for (int ct = 0; ct < CT; ct++) acc[ct] = (f32x4){0.f, 0.f, 0.f, 0.f};

  int rA = w * 16 + lr;
  #pragma unroll
  for (int k0 = 0; k0 < 4; k0++) {
    int slot = k0 * 4 + lg;
    bf16x8 a = *(const bf16x8*)((const char*)A_s + rA * 256 + ((slot ^ (rA & 7)) << 4));
    #pragma unroll
    for (int ct = 0; ct < CT; ct++) {
      int rB = ct * 16 + lr;
      bf16x8 b = *(const bf16x8*)((const char*)B_s + rB * 256 + ((slot ^ (rB & 7)) << 4));
      acc[ct] = __builtin_amdgcn_mfma_f32_16x16x32_bf16(a, b, acc[ct], 0, 0, 0);
    }
  }

  #pragma unroll
  for (int ct = 0; ct < CT; ct++) {
    #pragma unroll
    for (int j = 0; j < 4; j++) {
      int gr = row0 + w * 16 + lg * 4 + j;
      if (gr >= N) continue;
      int col = ct * 16 + lr;
      float v = acc[ct][j];
      if (col < DOUT)                 h[(size_t)gr * DOUT + col] = __float2bfloat16(v);
      else if (col < DOUT + HEADS)    als[(size_t)gr * HEADS + (col - DOUT)] = v;
      else if (col < DOUT + 2*HEADS)  ald[(size_t)gr * HEADS + (col - DOUT - HEADS)] = v;
    }
  }
}

// ---------------- aggregation, H=4 C=32: 32-lane group per node, BN-folded epilogue ----------------
__global__ __launch_bounds__(256) void k_agg4(const __hip_bfloat16* __restrict__ h, const float* __restrict__ als,
    const float* __restrict__ ald, const int* __restrict__ rs, const int* __restrict__ col,
    const float* __restrict__ Aarr, const float* __restrict__ Barr,
    __hip_bfloat16* __restrict__ out, int N) {
  __shared__ int svs[8][32];
  __shared__ float ps[8][32][4];
  int tid = threadIdx.x;
  int sub = tid & 31, gi = tid >> 5;
  int n = blockIdx.x * 8 + gi;
  if (n >= N) return;
  int row = rs[n], deg = rs[n + 1] - row;
  float4 ad4 = *(const float4*)(ald + (size_t)n * 4);
  int hh2 = sub >> 3;
  float acc0 = 0.f, acc1 = 0.f, acc2 = 0.f, acc3 = 0.f;
  float s0 = 0.f, s1 = 0.f, s2 = 0.f, s3 = 0.f;

  for (int base = 0; base < deg; base += 32) {
    int k = base + sub;
    int sv = 0; float q0 = 0.f, q1 = 0.f, q2 = 0.f, q3 = 0.f;
    if (k < deg) {
      sv = col[row + k];
      float4 a4 = *(const float4*)(als + (size_t)sv * 4);
      q0 = __expf(lrelu(a4.x + ad4.x));
      q1 = __expf(lrelu(a4.y + ad4.y));
      q2 = __expf(lrelu(a4.z + ad4.z));
      q3 = __expf(lrelu(a4.w + ad4.w));
    }
    svs[gi][sub] = sv;
    *(float4*)&ps[gi][sub][0] = make_float4(q0, q1, q2, q3);
    s0 += q0; s1 += q1; s2 += q2; s3 += q3;
    int cnt = min(32, deg - base);
    int e = 0;
    for (; e + 3 < cnt; e += 4) {
      float pA = ps[gi][e][hh2];     int sA = svs[gi][e];
      float pB = ps[gi][e + 1][hh2]; int sB = svs[gi][e + 1];
      float pC = ps[gi][e + 2][hh2]; int sC = svs[gi][e + 2];
      float pD = ps[gi][e + 3][hh2]; int sD = svs[gi][e + 3];
      uint2 hA = *((const uint2*)(h + (size_t)sA * 128) + sub);
      uint2 hB = *((const uint2*)(h + (size_t)sB * 128) + sub);
      uint2 hC = *((const uint2*)(h + (size_t)sC * 128) + sub);
      uint2 hD = *((const uint2*)(h + (size_t)sD * 128) + sub);
      acc0 = fmaf(pA, blo(hA.x), acc0); acc1 = fmaf(pA, bhi(hA.x), acc1);
      acc2 = fmaf(pA, blo(hA.y), acc2); acc3 = fmaf(pA, bhi(hA.y), acc3);
      acc0 = fmaf(pB, blo(hB.x), acc0); acc1 = fmaf(pB, bhi(hB.x), acc1);
      acc2 = fmaf(pB, blo(hB.y), acc2); acc3 = fmaf(pB, bhi(hB.y), acc3);
      acc0 = fmaf(pC, blo(hC.x), acc0); acc1 = fmaf(pC, bhi(hC.x), acc1);
      acc2 = fmaf(pC, blo(hC.y), acc2); acc3 = fmaf(pC, bhi(hC.y), acc3);
      acc0 = fmaf(pD, blo(hD.x), acc0); acc1 = fmaf(pD, bhi(hD.x), acc1);
      acc2 = fmaf(pD, blo(hD.y), acc2); acc3 = fmaf(pD, bhi(hD.y), acc3);
    }
    for (; e < cnt; e++) {
      float pA = ps[gi][e][hh2]; int sA = svs[gi][e];
      uint2 hA = *((const uint2*)(h + (size_t)sA * 128) + sub);
      acc0 = fmaf(pA, blo(hA.x), acc0); acc1 = fmaf(pA, bhi(hA.x), acc1);
      acc2 = fmaf(pA, blo(hA.y), acc2); acc3 = fmaf(pA, bhi(hA.y), acc3);
    }
  }
  #pragma unroll
  for (int off = 1; off < 32; off <<= 1) {
    s0 += __shfl_xor(s0, off); s1 += __shfl_xor(s1, off);
    s2 += __shfl_xor(s2, off); s3 += __shfl_xor(s3, off);
  }
  float ssel = hh2 == 0 ? s0 : hh2 == 1 ? s1 : hh2 == 2 ? s2 : s3;
  float inv = 1.f / (ssel + 1e-16f);

  int c0 = 4 * sub;
  float4 Av = *(const float4*)(Aarr + c0);
  float4 Bv = *(const float4*)(Barr + c0);
  float v0 = acc0 * inv * Av.x + Bv.x;
  float v1 = acc1 * inv * Av.y + Bv.y;
  float v2 = acc2 * inv * Av.z + Bv.z;
  float v3 = acc3 * inv * Av.w + Bv.w;
  v0 = elu_fast(v0); v1 = elu_fast(v1); v2 = elu_fast(v2); v3 = elu_fast(v3);
  uint2 packed;
  packed.x = ((unsigned int)f2bu(v1) << 16) | f2bu(v0);
  packed.y = ((unsigned int)f2bu(v3) << 16) | f2bu(v2);
  *((uint2*)((unsigned short*)out + (size_t)n * 128) + sub) = packed;
}

// ---------------- aggregation, H=1 C=32: 16-lane group per node, BN-folded ----------------
__global__ __launch_bounds__(256) void k_agg1(const __hip_bfloat16* __restrict__ h, const float* __restrict__ als,
    const float* __restrict__ ald, const int* __restrict__ rs, const int* __restrict__ col,
    const float* __restrict__ A2, const float* __restrict__ B2,
    __hip_bfloat16* __restrict__ out, int N) {
  __shared__ int svs[16][16];
  __shared__ float ps[16][16];
  int tid = threadIdx.x;
  int sub = tid & 15, gi = tid >> 4;
  int n = blockIdx.x * 16 + gi;
  if (n >= N) return;
  int row = rs[n], deg = rs[n + 1] - row;
  float ad = ald[n];
  float acc0 = 0.f, acc1 = 0.f, s = 0.f;

  for (int base = 0; base < deg; base += 16) {
    int k = base + sub;
    int sv = 0; float q = 0.f;
    if (k < deg) {
      sv = col[row + k];
      q = __expf(lrelu(als[sv] + ad));
    }
    svs[gi][sub] = sv;
    ps[gi][sub] = q;
    s += q;
    int cnt = min(16, deg - base);
    int e = 0;
    for (; e + 3 < cnt; e += 4) {
      float pA = ps[gi][e];     int sA = svs[gi][e];
      float pB = ps[gi][e + 1]; int sB = svs[gi][e + 1];
      float pC = ps[gi][e + 2]; int sC = svs[gi][e + 2];
      float pD = ps[gi][e + 3]; int sD = svs[gi][e + 3];
      unsigned int hA = *((const unsigned int*)(h + (size_t)sA * 32) + sub);
      unsigned int hB = *((const unsigned int*)(h + (size_t)sB * 32) + sub);
      unsigned int hC = *((const unsigned int*)(h + (size_t)sC * 32) + sub);
      unsigned int hD = *((const unsigned int*)(h + (size_t)sD * 32) + sub);
      acc0 = fmaf(pA, blo(hA), acc0); acc1 = fmaf(pA, bhi(hA), acc1);
      acc0 = fmaf(pB, blo(hB), acc0); acc1 = fmaf(pB, bhi(hB), acc1);
      acc0 = fmaf(pC, blo(hC), acc0); acc1 = fmaf(pC, bhi(hC), acc1);
      acc0 = fmaf(pD, blo(hD), acc0); acc1 = fmaf(pD, bhi(hD), acc1);
    }
    for (; e < cnt; e++) {
      float pA = ps[gi][e]; int sA = svs[gi][e];
      unsigned int hA = *((const unsigned int*)(h + (size_t)sA * 32) + sub);
      acc0 = fmaf(pA, blo(hA), acc0); acc1 = fmaf(pA, bhi(hA), acc1);
    }
  }
  #pragma unroll
  for (int off = 1; off < 16; off <<= 1) s += __shfl_xor(s, off);
  float inv = 1.f / (s + 1e-16f);

  int c0 = 2 * sub;
  float2 Af = *(const float2*)(A2 + c0);
  float2 Bf = *(const float2*)(B2 + c0);
  float v0 = acc0 * inv * Af.x + Bf.x;
  float v1 = acc1 * inv * Af.y + Bf.y;
  v0 = elu_fast(v0);
  v1 = elu_fast(v1);
  unsigned int packed = ((unsigned int)f2bu(v1) << 16) | f2bu(v0);
  *((unsigned int*)((unsigned short*)out + (size_t)n * 32) + sub) = packed;
}

// ---------------- per-graph pooling + MLP head (raw weights via flag) ----------------
__global__ __launch_bounds__(64) void k_pool(const __hip_bfloat16* __restrict__ x3, const int* __restrict__ batch,
    const void* __restrict__ u, const void* __restrict__ l1w,
    const void* __restrict__ l1b, const void* __restrict__ l2w,
    const void* __restrict__ l2b, const int* __restrict__ flag,
    float* __restrict__ out, int N, int G) {
  int g = blockIdx.x;
  int lane = threadIdx.x;
  int lo = 0, hi = N;
  while (lo < hi) { int mid = (lo + hi) >> 1; if (batch[mid] < g) lo = mid + 1; else hi = mid; }
  int start = lo;
  hi = N;
  while (lo < hi) { int mid = (lo + hi) >> 1; if (batch[mid] < g + 1) lo = mid + 1; else hi = mid; }
  int end = lo;
  int sub = lane & 15, q = lane >> 4;
  float sum0 = 0.f, sum1 = 0.f, mx0 = -1e30f, mx1 = -1e30f;
  for (int i = start + q; i < end; i += 4) {
    unsigned int hv = *((const unsigned int*)(x3 + (size_t)i * 32) + sub);
    float v0 = blo(hv), v1 = bhi(hv);
    sum0 += v0; sum1 += v1;
    mx0 = fmaxf(mx0, v0); mx1 = fmaxf(mx1, v1);
  }
  sum0 += __shfl_xor(sum0, 16); sum0 += __shfl_xor(sum0, 32);
  sum1 += __shfl_xor(sum1, 16); sum1 += __shfl_xor(sum1, 32);
  mx0 = fmaxf(mx0, __shfl_xor(mx0, 16)); mx0 = fmaxf(mx0, __shfl_xor(mx0, 32));
  mx1 = fmaxf(mx1, __shfl_xor(mx1, 16)); mx1 = fmaxf(mx1, __shfl_xor(mx1, 32));
  __shared__ float comb[74];
  int fl = *flag;
  if (lane < 16) {
    float cnt = (float)(end - start);
    comb[2 * lane] = sum0 / cnt;
    comb[2 * lane + 1] = sum1 / cnt;
    comb[32 + 2 * lane] = mx0;
    comb[32 + 2 * lane + 1] = mx1;
  }
  if (lane < 10) comb[64 + lane] = ldw(u, g * 10 + lane, fl);
  __syncthreads();
  if (lane < 32) {
    float acc = ldw(l1b, lane, fl);
    #pragma unroll
    for (int k = 0; k < 74; k++) acc = fmaf(comb[k], ldw(l1w, k * 32 + lane, fl), acc);
    acc = fmaxf(acc, 0.f);
    float v = acc * ldw(l2w, lane, fl);
    #pragma unroll
    for (int off = 16; off; off >>= 1) v += __shfl_xor(v, off, 32);
    if (lane == 0) out[g] = 1.f / (1.f + __expf(-(v + ldw(l2b, 0, fl))));
  }
}

extern "C" void kernel_launch(void* const* d_in, const int* in_sizes, int n_in,
                              void* d_out, int out_size, void* d_ws, size_t ws_size,
                              hipStream_t stream) {
  const int* EI    = (const int*)d_in[1];
  const int* BATCH = (const int*)d_in[2];
  float* OUT = (float*)d_out;

  int N = in_sizes[2];
  int E = in_sizes[1] / 2;
  int G = in_sizes[3] / 10;
  int EN = E + N;
  int NB = (N + 127) >> 7;
  int ebks = (EN + 4095) / 4096;

  char* ws = (char*)d_ws;
  size_t off = 0;
  auto alloc = [&](size_t bytes) {
    void* p = ws + off;
    off = (off + bytes + 255) & ~(size_t)255;
    return p;
  };
  __hip_bfloat16* f_xa = (__hip_bfloat16*)alloc((size_t)N * 128 * 2);
  __hip_bfloat16* f_h  = (__hip_bfloat16*)alloc((size_t)N * 128 * 2);
  float* f_als = (float*)alloc((size_t)N * 4 * 4);
  float* f_ald = (float*)alloc((size_t)N * 4 * 4);
  float* fW0p  = (float*)alloc(576 * 4);
  __hip_bfloat16* fWt1 = (__hip_bfloat16*)alloc(144 * 128 * 2);
  __hip_bfloat16* fWt2 = (__hip_bfloat16*)alloc(48 * 128 * 2);
  float* fA0 = (float*)alloc(128 * 4);
  float* fB0 = (float*)alloc(128 * 4);
  float* fA1 = (float*)alloc(128 * 4);
  float* fB1 = (float*)alloc(128 * 4);
  float* fA2 = (float*)alloc(32 * 4);
  float* fB2 = (float*)alloc(32 * 4);
  int* i_rs   = (int*)alloc((size_t)(N + 1) * 4);
  int* i_col  = (int*)alloc((size_t)EN * 4);
  unsigned int* i_pairs = (unsigned int*)alloc((size_t)EN * 4);
  int* i_ph      = (int*)alloc((size_t)ebks * 512 * 4);
  int* i_bbase   = (int*)alloc(513 * 4);
  int* i_gcursor = (int*)alloc(512 * 4);
  int* i_flag = (int*)alloc(256);

  // setup: dtype detect + per-block histograms
  k_setup<<<ebks + 1, 256, 0, stream>>>(EI, E, EN, ebks,
                                        (const unsigned short*)d_in[12], in_sizes[12],
                                        i_flag, i_ph);
  // weight folding (raw inputs, needs flag)
  FoldArgs fa;
  fa.W0 = d_in[4];  fa.as0 = d_in[5];  fa.ad0 = d_in[6];
  fa.W1 = d_in[12]; fa.as1 = d_in[13]; fa.ad1 = d_in[14];
  fa.W2 = d_in[20]; fa.as2 = d_in[21]; fa.ad2 = d_in[22];
  for (int i = 0; i < 5; i++) {
    fa.bn[i]      = d_in[7 + i];
    fa.bn[5 + i]  = d_in[15 + i];
    fa.bn[10 + i] = d_in[23 + i];
  }
  fa.W0p = fW0p; fa.Wt1 = fWt1; fa.Wt2 = fWt2;
  fa.A0 = fA0; fa.B0 = fB0; fa.A1 = fA1; fa.B1 = fB1; fa.A2 = fA2; fa.B2 = fB2;
  k_foldW<<<100, 256, 0, stream>>>(fa, i_flag);

  // CSR build
  k_bucketscan<<<1, 512, 0, stream>>>(i_ph, ebks, i_bbase, i_gcursor);
  k_binscatter<<<ebks, 256, 0, stream>>>(EI, i_gcursor, i_pairs, E, EN);
  k_csrfin<<<NB, 256, 0, stream>>>(i_pairs, i_bbase, i_rs, i_col, N, EN);

  // layer 0
  k_gemm0<<<(N * 36 + 255) / 256, 256, 0, stream>>>(d_in[0], fW0p, i_flag, f_h, f_als, f_ald, N);
  k_agg4<<<(N + 7) / 8, 256, 0, stream>>>(f_h, f_als, f_ald, i_rs, i_col, fA0, fB0, f_xa, N);
  // layer 1 (MFMA)
  k_mm<9, 128, 4><<<(N + 63) / 64, 256, 0, stream>>>(f_xa, fWt1, f_h, f_als, f_ald, N);
  k_agg4<<<(N + 7) / 8, 256, 0, stream>>>(f_h, f_als, f_ald, i_rs, i_col, fA1, fB1, f_xa, N);
  // layer 2 (MFMA)
  k_mm<3, 32, 1><<<(N + 63) / 64, 256, 0, stream>>>(f_xa, fWt2, f_h, f_als, f_ald, N);
  k_agg1<<<(N + 15) / 16, 256, 0, stream>>>(f_h, f_als, f_ald, i_rs, i_col, fA2, fB2, f_xa, N);

  // pooling + MLP head
  k_pool<<<G, 64, 0, stream>>>(f_xa, BATCH, d_in[3], d_in[28], d_in[29], d_in[30], d_in[31],
                               i_flag, OUT, N, G);
}

// Round 15
// 192.008 us; speedup vs baseline: 1.1250x; 1.1003x over previous
//
#include <hip/hip_runtime.h>
#include <hip/hip_bf16.h>
#include <math.h>

#define LRELU_NEG 0.2f
#define BN_EPS 1e-5f
#define CSR_SHIFT 7

typedef __attribute__((ext_vector_type(8))) short bf16x8;
typedef __attribute__((ext_vector_type(4))) float f32x4;

__device__ __forceinline__ float lrelu(float x) { return x > 0.f ? x : LRELU_NEG * x; }
__device__ __forceinline__ float b2f(__hip_bfloat16 v) { return __bfloat162float(v); }
__device__ __forceinline__ unsigned short f2bu(float v) {
  __hip_bfloat16 b = __float2bfloat16(v);
  return *(unsigned short*)&b;
}
__device__ __forceinline__ float blo(unsigned int u) { return __uint_as_float(u << 16); }
__device__ __forceinline__ float bhi(unsigned int u) { return __uint_as_float(u & 0xFFFF0000u); }
__device__ __forceinline__ float elu_fast(float v) { return v > 0.f ? v : __expf(v) - 1.f; }

// ---------------- dtype detection (+ ghist zeroing) ----------------
__global__ __launch_bounds__(256) void k_detect(const unsigned short* __restrict__ w, int n,
                                                int* __restrict__ flag, int* __restrict__ ghist) {
  __shared__ int bad_s;
  int tid = threadIdx.x;
  ghist[tid] = 0; ghist[tid + 256] = 0;
  if (tid == 0) bad_s = 0;
  __syncthreads();
  int bad = 0;
  for (int i = 2 * tid; i < n; i += 512) {
    unsigned short u = w[i];
    if ((u & 0x7FFF) == 0) continue;
    int ex = (u >> 7) & 0xFF;
    if (ex > 131 || ex < 90) bad++;
  }
  atomicAdd(&bad_s, bad);
  __syncthreads();
  if (tid == 0) *flag = (bad_s < 2048) ? 1 : 0;
}

// ---------------- unified input conversion -> f32 in ws ----------------
struct CvtArgs {
  const void* src[30];
  float* dst[30];
  int n[30];
};

__global__ __launch_bounds__(256) void k_cvt_all(CvtArgs a, const int* __restrict__ flag) {
  int ai = blockIdx.y;
  int n = a.n[ai];
  int i = blockIdx.x * 256 + threadIdx.x;
  if (i >= n) return;
  if (*flag) {
    a.dst[ai][i] = b2f(((const __hip_bfloat16*)a.src[ai])[i]);
  } else {
    a.dst[ai][i] = ((const float*)a.src[ai])[i];
  }
}

// ---------------- weight folding ----------------
__global__ __launch_bounds__(256) void k_foldW(const float* __restrict__ W0, const float* __restrict__ as0, const float* __restrict__ ad0,
                                               const float* __restrict__ W1, const float* __restrict__ as1, const float* __restrict__ ad1,
                                               const float* __restrict__ W2, const float* __restrict__ as2, const float* __restrict__ ad2,
                                               float* __restrict__ W0p, __hip_bfloat16* __restrict__ Wt1, __hip_bfloat16* __restrict__ Wt2) {
  int idx = blockIdx.x * 256 + threadIdx.x;
  if (idx < 576) {                  // W0p [4][144]
    int k = idx / 144, c = idx % 144;
    float v = 0.f;
    if (c < 128) v = W0[k * 128 + c];
    else if (c < 136) {
      int hh = (c - 128) & 3; const float* a = (c < 132) ? as0 : ad0;
      float s = 0.f;
      for (int cc = 0; cc < 32; cc++) s += W0[k * 128 + hh * 32 + cc] * a[hh * 32 + cc];
      v = s;
    }
    W0p[k * 144 + c] = v;
    return;
  }
  idx -= 576;
  if (idx < 144 * 128) {            // Wt1 [144][128]
    int c = idx >> 7, k = idx & 127;
    float v = 0.f;
    if (c < 128) v = W1[k * 128 + c];
    else if (c < 136) {
      int hh = (c - 128) & 3; const float* a = (c < 132) ? as1 : ad1;
      float s = 0.f;
      for (int cc = 0; cc < 32; cc++) s += W1[k * 128 + hh * 32 + cc] * a[hh * 32 + cc];
      v = s;
    }
    Wt1[c * 128 + k] = __float2bfloat16(v);
    return;
  }
  idx -= 144 * 128;
  if (idx < 48 * 128) {             // Wt2 [48][128]
    int c = idx >> 7, k = idx & 127;
    float v = 0.f;
    if (c < 32) v = W2[k * 32 + c];
    else if (c == 32) { float s = 0.f; for (int cc = 0; cc < 32; cc++) s += W2[k * 32 + cc] * as2[cc]; v = s; }
    else if (c == 33) { float s = 0.f; for (int cc = 0; cc < 32; cc++) s += W2[k * 32 + cc] * ad2[cc]; v = s; }
    Wt2[c * 128 + k] = __float2bfloat16(v);
  }
}

// ================= bucketed CSR build =================
__global__ __launch_bounds__(256) void k_binhist(const int* __restrict__ ei, int* __restrict__ ghist,
                                                 int E, int EN) {
  __shared__ int hist[512];
  int tid = threadIdx.x;
  hist[tid] = 0; hist[tid + 256] = 0;
  __syncthreads();
  int base = blockIdx.x * 4096;
  for (int i = 0; i < 16; i++) {
    int e = base + i * 256 + tid;
    if (e < EN) {
      int dst = (e < E) ? ei[E + e] : (e - E);
      atomicAdd(&hist[dst >> CSR_SHIFT], 1);
    }
  }
  __syncthreads();
  if (hist[tid]) atomicAdd(&ghist[tid], hist[tid]);
  if (hist[tid + 256]) atomicAdd(&ghist[tid + 256], hist[tid + 256]);
}

__global__ __launch_bounds__(512) void k_bucketscan(const int* __restrict__ ghist,
                                                    int* __restrict__ bbase, int* __restrict__ gcursor) {
  __shared__ int wpre[8];
  int tid = threadIdx.x, lane = tid & 63, wid = tid >> 6;
  int v = ghist[tid];
  int x = v;
  #pragma unroll
  for (int off = 1; off < 64; off <<= 1) {
    int y = __shfl_up(x, off);
    if (lane >= off) x += y;
  }
  if (lane == 63) wpre[wid] = x;
  __syncthreads();
  if (tid == 0) {
    int acc = 0;
    #pragma unroll
    for (int w = 0; w < 8; w++) { int t = wpre[w]; wpre[w] = acc; acc += t; }
  }
  __syncthreads();
  int excl = wpre[wid] + x - v;
  bbase[tid] = excl;
  gcursor[tid] = excl;
  if (tid == 511) bbase[512] = excl + v;
}

__global__ __launch_bounds__(256) void k_binscatter(const int* __restrict__ ei, int* __restrict__ gcursor,
                                                    unsigned int* __restrict__ pairs, int E, int EN) {
  __shared__ int cnt[512];
  __shared__ int base[512];
  int tid = threadIdx.x;
  cnt[tid] = 0; cnt[tid + 256] = 0;
  __syncthreads();
  int eb = blockIdx.x * 4096;
  int srcs[16], dsts[16];
  #pragma unroll
  for (int i = 0; i < 16; i++) {
    int e = eb + i * 256 + tid;
    srcs[i] = -1; dsts[i] = 0;
    if (e < EN) {
      int s, d;
      if (e < E) { s = ei[e]; d = ei[E + e]; } else { s = e - E; d = s; }
      srcs[i] = s; dsts[i] = d;
      atomicAdd(&cnt[d >> CSR_SHIFT], 1);
    }
  }
  __syncthreads();
  for (int b = tid; b < 512; b += 256) {
    int c = cnt[b];
    base[b] = c ? atomicAdd(&gcursor[b], c) : 0;
    cnt[b] = 0;
  }
  __syncthreads();
  #pragma unroll
  for (int i = 0; i < 16; i++) {
    if (srcs[i] >= 0) {
      int b = dsts[i] >> CSR_SHIFT;
      int loc = atomicAdd(&cnt[b], 1);
      pairs[base[b] + loc] = ((unsigned int)srcs[i] << CSR_SHIFT) | (unsigned int)(dsts[i] & 127);
    }
  }
}

// merged: per-bucket degree histogram + 128-scan -> rs, then scatter col (one kernel)
__global__ __launch_bounds__(256) void k_csrfin(const unsigned int* __restrict__ pairs,
                                                const int* __restrict__ bbase,
                                                int* __restrict__ rs, int* __restrict__ col,
                                                int N, int EN) {
  __shared__ int dcount[128];
  __shared__ int wsum;
  __shared__ int lcur[128];
  int b = blockIdx.x, tid = threadIdx.x;
  if (tid < 128) dcount[tid] = 0;
  __syncthreads();
  int s = bbase[b], e = bbase[b + 1];
  for (int i = s + tid; i < e; i += 256)
    atomicAdd(&dcount[pairs[i] & 127], 1);
  __syncthreads();
  int x = 0, v = 0, wid = 0;
  if (tid < 128) {
    v = dcount[tid];
    int lane = tid & 63; wid = tid >> 6;
    x = v;
    #pragma unroll
    for (int off = 1; off < 64; off <<= 1) {
      int y = __shfl_up(x, off);
      if (lane >= off) x += y;
    }
    if (wid == 0 && lane == 63) wsum = x;
  }
  __syncthreads();
  if (tid < 128) {
    int excl = x - v + (wid ? wsum : 0);
    int r = s + excl;
    int node = (b << CSR_SHIFT) + tid;
    if (node < N) rs[node] = r;
    lcur[tid] = r;
  }
  if (b == 0 && tid == 0) rs[N] = EN;
  __syncthreads();
  for (int i = s + tid; i < e; i += 256) {
    unsigned int p = pairs[i];
    int pos = atomicAdd(&lcur[p & 127], 1);
    col[pos] = (int)(p >> CSR_SHIFT);
  }
}

// ---------------- layer-0 GEMM (K=4), folded logits, 4 outputs/thread ----------------
__global__ __launch_bounds__(256) void k_gemm0(const float* __restrict__ x, const float* __restrict__ W0p,
    __hip_bfloat16* __restrict__ h, float* __restrict__ als, float* __restrict__ ald, int N) {
  int t = blockIdx.x * 256 + threadIdx.x;
  int nrow = t / 36, cg = t - nrow * 36;
  if (nrow >= N) return;
  float4 xv = *(const float4*)(x + (size_t)nrow * 4);
  int c0 = cg * 4;
  float o[4];
  #pragma unroll
  for (int j = 0; j < 4; j++) {
    int c = c0 + j;
    o[j] = fmaf(xv.x, W0p[c], fmaf(xv.y, W0p[144 + c], fmaf(xv.z, W0p[288 + c], xv.w * W0p[432 + c])));
  }
  if (c0 < 128) {
    uint2 pk;
    pk.x = ((unsigned int)f2bu(o[1]) << 16) | f2bu(o[0]);
    pk.y = ((unsigned int)f2bu(o[3]) << 16) | f2bu(o[2]);
    *((uint2*)((unsigned short*)h + (size_t)nrow * 128) + cg) = pk;
  } else if (c0 == 128) {
    *(float4*)(als + (size_t)nrow * 4) = make_float4(o[0], o[1], o[2], o[3]);
  } else {   // c0 == 132
    *(float4*)(ald + (size_t)nrow * 4) = make_float4(o[0], o[1], o[2], o[3]);
  }
}

// ---------------- MFMA GEMM ----------------
template <int CT, int DOUT, int HEADS>
__global__ __launch_bounds__(256) void k_mm(const __hip_bfloat16* __restrict__ xa,
    const __hip_bfloat16* __restrict__ Wt,
    __hip_bfloat16* __restrict__ h, float* __restrict__ als, float* __restrict__ ald, int N) {
  __shared__ unsigned short A_s[64 * 128];
  __shared__ unsigned short B_s[CT * 16 * 128];
  int tid = threadIdx.x;
  int row0 = blockIdx.x * 64;

  for (int i = tid; i < 1024; i += 256) {
    int r = i >> 4, slot = i & 15;
    int gr = row0 + r;
    float4 v = make_float4(0.f, 0.f, 0.f, 0.f);
    if (gr < N) v = ((const float4*)(xa + (size_t)gr * 128))[slot];
    *(float4*)((char*)A_s + r * 256 + ((slot ^ (r & 7)) << 4)) = v;
  }
  for (int i = tid; i < CT * 256; i += 256) {
    int r = i >> 4, slot = i & 15;
    float4 v = ((const float4*)Wt)[i];
    *(float4*)((char*)B_s + r * 256 + ((slot ^ (r & 7)) << 4)) = v;
  }
  __syncthreads();

  int l = tid & 63, w = tid >> 6;
  int lr = l & 15, lg = l >> 4;
  f32x4 acc[CT];
  #pragma unroll
  for (int ct = 0; ct < CT; ct++) acc[ct] = (f32x4){0.f, 0.f, 0.f, 0.f};

  int rA = w * 16 + lr;
  #pragma unroll
  for (int k0 = 0; k0 < 4; k0++) {
    int slot = k0 * 4 + lg;
    bf16x8 a = *(const bf16x8*)((const char*)A_s + rA * 256 + ((slot ^ (rA & 7)) << 4));
    #pragma unroll
    for (int ct = 0; ct < CT; ct++) {
      int rB = ct * 16 + lr;
      bf16x8 b = *(const bf16x8*)((const char*)B_s + rB * 256 + ((slot ^ (rB & 7)) << 4));
      acc[ct] = __builtin_amdgcn_mfma_f32_16x16x32_bf16(a, b, acc[ct], 0, 0, 0);
    }
  }

  #pragma unroll
  for (int ct = 0; ct < CT; ct++) {
    #pragma unroll
    for (int j = 0; j < 4; j++) {
      int gr = row0 + w * 16 + lg * 4 + j;
      if (gr >= N) continue;
      int col = ct * 16 + lr;
      float v = acc[ct][j];
      if (col < DOUT)                 h[(size_t)gr * DOUT + col] = __float2bfloat16(v);
      else if (col < DOUT + HEADS)    als[(size_t)gr * HEADS + (col - DOUT)] = v;
      else if (col < DOUT + 2*HEADS)  ald[(size_t)gr * HEADS + (col - DOUT - HEADS)] = v;
    }
  }
}

// ---------------- aggregation, H=4 C=32: 32-lane group per node, unroll-4 gather ----------------
__global__ __launch_bounds__(256) void k_agg4(const __hip_bfloat16* __restrict__ h, const float* __restrict__ als,
    const float* __restrict__ ald, const int* __restrict__ rs, const int* __restrict__ col,
    const float* __restrict__ bias, const float* __restrict__ bng,
    const float* __restrict__ bnb, const float* __restrict__ bnm,
    const float* __restrict__ bnv, __hip_bfloat16* __restrict__ out, int N) {
  __shared__ int svs[8][32];
  __shared__ float ps[8][32][4];
  int tid = threadIdx.x;
  int sub = tid & 31, gi = tid >> 5;
  int n = blockIdx.x * 8 + gi;
  if (n >= N) return;
  int row = rs[n], deg = rs[n + 1] - row;
  float4 ad4 = *(const float4*)(ald + (size_t)n * 4);
  int hh2 = sub >> 3;
  float acc0 = 0.f, acc1 = 0.f, acc2 = 0.f, acc3 = 0.f;
  float s0 = 0.f, s1 = 0.f, s2 = 0.f, s3 = 0.f;

  for (int base = 0; base < deg; base += 32) {
    int k = base + sub;
    int sv = 0; float q0 = 0.f, q1 = 0.f, q2 = 0.f, q3 = 0.f;
    if (k < deg) {
      sv = col[row + k];
      float4 a4 = *(const float4*)(als + (size_t)sv * 4);
      q0 = __expf(lrelu(a4.x + ad4.x));
      q1 = __expf(lrelu(a4.y + ad4.y));
      q2 = __expf(lrelu(a4.z + ad4.z));
      q3 = __expf(lrelu(a4.w + ad4.w));
    }
    svs[gi][sub] = sv;
    *(float4*)&ps[gi][sub][0] = make_float4(q0, q1, q2, q3);
    s0 += q0; s1 += q1; s2 += q2; s3 += q3;
    int cnt = min(32, deg - base);
    int e = 0;
    for (; e + 3 < cnt; e += 4) {
      float pA = ps[gi][e][hh2];     int sA = svs[gi][e];
      float pB = ps[gi][e + 1][hh2]; int sB = svs[gi][e + 1];
      float pC = ps[gi][e + 2][hh2]; int sC = svs[gi][e + 2];
      float pD = ps[gi][e + 3][hh2]; int sD = svs[gi][e + 3];
      uint2 hA = *((const uint2*)(h + (size_t)sA * 128) + sub);
      uint2 hB = *((const uint2*)(h + (size_t)sB * 128) + sub);
      uint2 hC = *((const uint2*)(h + (size_t)sC * 128) + sub);
      uint2 hD = *((const uint2*)(h + (size_t)sD * 128) + sub);
      acc0 = fmaf(pA, blo(hA.x), acc0); acc1 = fmaf(pA, bhi(hA.x), acc1);
      acc2 = fmaf(pA, blo(hA.y), acc2); acc3 = fmaf(pA, bhi(hA.y), acc3);
      acc0 = fmaf(pB, blo(hB.x), acc0); acc1 = fmaf(pB, bhi(hB.x), acc1);
      acc2 = fmaf(pB, blo(hB.y), acc2); acc3 = fmaf(pB, bhi(hB.y), acc3);
      acc0 = fmaf(pC, blo(hC.x), acc0); acc1 = fmaf(pC, bhi(hC.x), acc1);
      acc2 = fmaf(pC, blo(hC.y), acc2); acc3 = fmaf(pC, bhi(hC.y), acc3);
      acc0 = fmaf(pD, blo(hD.x), acc0); acc1 = fmaf(pD, bhi(hD.x), acc1);
      acc2 = fmaf(pD, blo(hD.y), acc2); acc3 = fmaf(pD, bhi(hD.y), acc3);
    }
    for (; e < cnt; e++) {
      float pA = ps[gi][e][hh2]; int sA = svs[gi][e];
      uint2 hA = *((const uint2*)(h + (size_t)sA * 128) + sub);
      acc0 = fmaf(pA, blo(hA.x), acc0); acc1 = fmaf(pA, bhi(hA.x), acc1);
      acc2 = fmaf(pA, blo(hA.y), acc2); acc3 = fmaf(pA, bhi(hA.y), acc3);
    }
  }
  #pragma unroll
  for (int off = 1; off < 32; off <<= 1) {
    s0 += __shfl_xor(s0, off); s1 += __shfl_xor(s1, off);
    s2 += __shfl_xor(s2, off); s3 += __shfl_xor(s3, off);
  }
  float ssel = hh2 == 0 ? s0 : hh2 == 1 ? s1 : hh2 == 2 ? s2 : s3;
  float inv = 1.f / (ssel + 1e-16f);
  acc0 *= inv; acc1 *= inv; acc2 *= inv; acc3 *= inv;

  int c0 = 4 * sub;
  float4 bi = *(const float4*)(bias + c0);
  float4 bm = *(const float4*)(bnm + c0);
  float4 bv = *(const float4*)(bnv + c0);
  float4 bg = *(const float4*)(bng + c0);
  float4 bb = *(const float4*)(bnb + c0);
  float v0 = (acc0 + bi.x - bm.x) * rsqrtf(bv.x + BN_EPS) * bg.x + bb.x;
  float v1 = (acc1 + bi.y - bm.y) * rsqrtf(bv.y + BN_EPS) * bg.y + bb.y;
  float v2 = (acc2 + bi.z - bm.z) * rsqrtf(bv.z + BN_EPS) * bg.z + bb.z;
  float v3 = (acc3 + bi.w - bm.w) * rsqrtf(bv.w + BN_EPS) * bg.w + bb.w;
  v0 = elu_fast(v0); v1 = elu_fast(v1); v2 = elu_fast(v2); v3 = elu_fast(v3);
  uint2 packed;
  packed.x = ((unsigned int)f2bu(v1) << 16) | f2bu(v0);
  packed.y = ((unsigned int)f2bu(v3) << 16) | f2bu(v2);
  *((uint2*)((unsigned short*)out + (size_t)n * 128) + sub) = packed;
}

// ---------------- aggregation, H=1 C=32: 16-lane group per node, unroll-4 gather ----------------
__global__ __launch_bounds__(256) void k_agg1(const __hip_bfloat16* __restrict__ h, const float* __restrict__ als,
    const float* __restrict__ ald, const int* __restrict__ rs, const int* __restrict__ col,
    const float* __restrict__ bias, const float* __restrict__ bng,
    const float* __restrict__ bnb, const float* __restrict__ bnm,
    const float* __restrict__ bnv, __hip_bfloat16* __restrict__ out, int N) {
  __shared__ int svs[16][16];
  __shared__ float ps[16][16];
  int tid = threadIdx.x;
  int sub = tid & 15, gi = tid >> 4;
  int n = blockIdx.x * 16 + gi;
  if (n >= N) return;
  int row = rs[n], deg = rs[n + 1] - row;
  float ad = ald[n];
  float acc0 = 0.f, acc1 = 0.f, s = 0.f;

  for (int base = 0; base < deg; base += 16) {
    int k = base + sub;
    int sv = 0; float q = 0.f;
    if (k < deg) {
      sv = col[row + k];
      q = __expf(lrelu(als[sv] + ad));
    }
    svs[gi][sub] = sv;
    ps[gi][sub] = q;
    s += q;
    int cnt = min(16, deg - base);
    int e = 0;
    for (; e + 3 < cnt; e += 4) {
      float pA = ps[gi][e];     int sA = svs[gi][e];
      float pB = ps[gi][e + 1]; int sB = svs[gi][e + 1];
      float pC = ps[gi][e + 2]; int sC = svs[gi][e + 2];
      float pD = ps[gi][e + 3]; int sD = svs[gi][e + 3];
      unsigned int hA = *((const unsigned int*)(h + (size_t)sA * 32) + sub);
      unsigned int hB = *((const unsigned int*)(h + (size_t)sB * 32) + sub);
      unsigned int hC = *((const unsigned int*)(h + (size_t)sC * 32) + sub);
      unsigned int hD = *((const unsigned int*)(h + (size_t)sD * 32) + sub);
      acc0 = fmaf(pA, blo(hA), acc0); acc1 = fmaf(pA, bhi(hA), acc1);
      acc0 = fmaf(pB, blo(hB), acc0); acc1 = fmaf(pB, bhi(hB), acc1);
      acc0 = fmaf(pC, blo(hC), acc0); acc1 = fmaf(pC, bhi(hC), acc1);
      acc0 = fmaf(pD, blo(hD), acc0); acc1 = fmaf(pD, bhi(hD), acc1);
    }
    for (; e < cnt; e++) {
      float pA = ps[gi][e]; int sA = svs[gi][e];
      unsigned int hA = *((const unsigned int*)(h + (size_t)sA * 32) + sub);
      acc0 = fmaf(pA, blo(hA), acc0); acc1 = fmaf(pA, bhi(hA), acc1);
    }
  }
  #pragma unroll
  for (int off = 1; off < 16; off <<= 1) s += __shfl_xor(s, off);
  float inv = 1.f / (s + 1e-16f);
  acc0 *= inv; acc1 *= inv;

  int c0 = 2 * sub;
  float2 bi = *(const float2*)(bias + c0);
  float2 bm = *(const float2*)(bnm + c0);
  float2 bv = *(const float2*)(bnv + c0);
  float2 bg = *(const float2*)(bng + c0);
  float2 bb = *(const float2*)(bnb + c0);
  float v0 = (acc0 + bi.x - bm.x) * rsqrtf(bv.x + BN_EPS) * bg.x + bb.x;
  float v1 = (acc1 + bi.y - bm.y) * rsqrtf(bv.y + BN_EPS) * bg.y + bb.y;
  v0 = elu_fast(v0);
  v1 = elu_fast(v1);
  unsigned int packed = ((unsigned int)f2bu(v1) << 16) | f2bu(v0);
  *((unsigned int*)((unsigned short*)out + (size_t)n * 32) + sub) = packed;
}

// ---------------- per-graph pooling + MLP head ----------------
__global__ __launch_bounds__(64) void k_pool(const __hip_bfloat16* __restrict__ x3, const int* __restrict__ batch,
    const float* __restrict__ u, const float* __restrict__ l1w,
    const float* __restrict__ l1b, const float* __restrict__ l2w,
    const float* __restrict__ l2b, float* __restrict__ out, int N, int G) {
  int g = blockIdx.x;
  int lane = threadIdx.x;
  int lo = 0, hi = N;
  while (lo < hi) { int mid = (lo + hi) >> 1; if (batch[mid] < g) lo = mid + 1; else hi = mid; }
  int start = lo;
  hi = N;
  while (lo < hi) { int mid = (lo + hi) >> 1; if (batch[mid] < g + 1) lo = mid + 1; else hi = mid; }
  int end = lo;
  int sub = lane & 15, q = lane >> 4;
  float sum0 = 0.f, sum1 = 0.f, mx0 = -1e30f, mx1 = -1e30f;
  for (int i = start + q; i < end; i += 4) {
    unsigned int hv = *((const unsigned int*)(x3 + (size_t)i * 32) + sub);
    float v0 = blo(hv), v1 = bhi(hv);
    sum0 += v0; sum1 += v1;
    mx0 = fmaxf(mx0, v0); mx1 = fmaxf(mx1, v1);
  }
  sum0 += __shfl_xor(sum0, 16); sum0 += __shfl_xor(sum0, 32);
  sum1 += __shfl_xor(sum1, 16); sum1 += __shfl_xor(sum1, 32);
  mx0 = fmaxf(mx0, __shfl_xor(mx0, 16)); mx0 = fmaxf(mx0, __shfl_xor(mx0, 32));
  mx1 = fmaxf(mx1, __shfl_xor(mx1, 16)); mx1 = fmaxf(mx1, __shfl_xor(mx1, 32));
  __shared__ float comb[74];
  if (lane < 16) {
    float cnt = (float)(end - start);
    comb[2 * lane] = sum0 / cnt;
    comb[2 * lane + 1] = sum1 / cnt;
    comb[32 + 2 * lane] = mx0;
    comb[32 + 2 * lane + 1] = mx1;
  }
  if (lane < 10) comb[64 + lane] = u[g * 10 + lane];
  __syncthreads();
  if (lane < 32) {
    float acc = l1b[lane];
    #pragma unroll
    for (int k = 0; k < 74; k++) acc = fmaf(comb[k], l1w[k * 32 + lane], acc);
    acc = fmaxf(acc, 0.f);
    float v = acc * l2w[lane];
    #pragma unroll
    for (int off = 16; off; off >>= 1) v += __shfl_xor(v, off, 32);
    if (lane == 0) out[g] = 1.f / (1.f + __expf(-(v + l2b[0])));
  }
}

extern "C" void kernel_launch(void* const* d_in, const int* in_sizes, int n_in,
                              void* d_out, int out_size, void* d_ws, size_t ws_size,
                              hipStream_t stream) {
  const int* EI    = (const int*)d_in[1];
  const int* BATCH = (const int*)d_in[2];
  float* OUT = (float*)d_out;

  int N = in_sizes[2];
  int E = in_sizes[1] / 2;
  int G = in_sizes[3] / 10;
  int EN = E + N;
  int NB = (N + 127) >> 7;
  int ebks = (EN + 4095) / 4096;

  char* ws = (char*)d_ws;
  size_t off = 0;
  auto alloc = [&](size_t bytes) {
    void* p = ws + off;
    off = (off + bytes + 255) & ~(size_t)255;
    return p;
  };
  __hip_bfloat16* f_xa = (__hip_bfloat16*)alloc((size_t)N * 128 * 2);
  __hip_bfloat16* f_h  = (__hip_bfloat16*)alloc((size_t)N * 128 * 2);
  float* f_als = (float*)alloc((size_t)N * 4 * 4);
  float* f_ald = (float*)alloc((size_t)N * 4 * 4);
  float* fW0p  = (float*)alloc(576 * 4);
  __hip_bfloat16* fWt1 = (__hip_bfloat16*)alloc(144 * 128 * 2);
  __hip_bfloat16* fWt2 = (__hip_bfloat16*)alloc(48 * 128 * 2);
  int* i_rs   = (int*)alloc((size_t)(N + 1) * 4);
  int* i_col  = (int*)alloc((size_t)EN * 4);
  unsigned int* i_pairs = (unsigned int*)alloc((size_t)EN * 4);
  int* i_ghist   = (int*)alloc(512 * 4);
  int* i_bbase   = (int*)alloc(513 * 4);
  int* i_gcursor = (int*)alloc(512 * 4);
  int* i_flag = (int*)alloc(256);

  CvtArgs ca;
  float* fptr[32];
  int maxn = 0, na = 0;
  for (int i = 0; i < 32; i++) {
    if (i == 1 || i == 2) { fptr[i] = nullptr; continue; }
    int n = in_sizes[i];
    fptr[i] = (float*)alloc((size_t)n * 4);
    ca.src[na] = d_in[i];
    ca.dst[na] = fptr[i];
    ca.n[na] = n;
    if (n > maxn) maxn = n;
    na++;
  }

  // dtype detect (+ ghist zero) + convert
  k_detect<<<1, 256, 0, stream>>>((const unsigned short*)d_in[12], in_sizes[12], i_flag, i_ghist);
  dim3 cgrid((maxn + 255) / 256, na);
  k_cvt_all<<<cgrid, 256, 0, stream>>>(ca, i_flag);

  // weight folding
  k_foldW<<<99, 256, 0, stream>>>(fptr[4], fptr[5], fptr[6],
                                  fptr[12], fptr[13], fptr[14],
                                  fptr[20], fptr[21], fptr[22],
                                  fW0p, fWt1, fWt2);

  // bucketed CSR build
  k_binhist<<<ebks, 256, 0, stream>>>(EI, i_ghist, E, EN);
  k_bucketscan<<<1, 512, 0, stream>>>(i_ghist, i_bbase, i_gcursor);
  k_binscatter<<<ebks, 256, 0, stream>>>(EI, i_gcursor, i_pairs, E, EN);
  k_csrfin<<<NB, 256, 0, stream>>>(i_pairs, i_bbase, i_rs, i_col, N, EN);

  // layer 0
  k_gemm0<<<(N * 36 + 255) / 256, 256, 0, stream>>>(fptr[0], fW0p, f_h, f_als, f_ald, N);
  k_agg4<<<(N + 7) / 8, 256, 0, stream>>>(f_h, f_als, f_ald, i_rs, i_col, fptr[7], fptr[8], fptr[9], fptr[10], fptr[11], f_xa, N);
  // layer 1 (MFMA)
  k_mm<9, 128, 4><<<(N + 63) / 64, 256, 0, stream>>>(f_xa, fWt1, f_h, f_als, f_ald, N);
  k_agg4<<<(N + 7) / 8, 256, 0, stream>>>(f_h, f_als, f_ald, i_rs, i_col, fptr[15], fptr[16], fptr[17], fptr[18], fptr[19], f_xa, N);
  // layer 2 (MFMA)
  k_mm<3, 32, 1><<<(N + 63) / 64, 256, 0, stream>>>(f_xa, fWt2, f_h, f_als, f_ald, N);
  k_agg1<<<(N + 15) / 16, 256, 0, stream>>>(f_h, f_als, f_ald, i_rs, i_col, fptr[23], fptr[24], fptr[25], fptr[26], fptr[27], f_xa, N);

  // pooling + MLP head
  k_pool<<<G, 64, 0, stream>>>(f_xa, BATCH, fptr[3], fptr[28], fptr[29], fptr[30], fptr[31], OUT, N, G);
}